// Round 6
// baseline (130.503 us; speedup 1.0000x reference)
//
#include <hip/hip_runtime.h>
#include <cstdint>
#include <cstddef>

#define B_ 4
#define L_ 4096
#define E_ 1024
#define H_ 16
#define D_ 64
#define BH_ (B_*H_)
#define STATE_ (65*64)   // rows 0..63 = kv[d][e], row 64 = ksum[d]

__device__ __forceinline__ float sigk(float x) {
    // sigmoid(0.6053*x - 4.102) = 1/(1+exp(4.102 - 0.6053*x))
    return __builtin_amdgcn_rcpf(1.0f + __expf(4.102f - 0.6053f * x));
}

// ---------------- Kernel 1: partial KV state per (b,h,chunk) ----------------
// 1024 blocks, 32 KB LDS, 4 waves. Wave w owns output quadrant
// (d in [Dw,Dw+32), e in [Ew,Ew+32)) and sweeps ALL 64 rows of each staged
// tile -> acc is only 4x4/lane (no spill), and no inter-wave reduce.
__global__ void __launch_bounds__(256) kv_partial_kernel(
    const float* __restrict__ K, const float* __restrict__ V,
    float* __restrict__ partial, int nch, int rowsPerCh)
{
    __shared__ float Kt[4096];   // 64 x 64 phi(K)
    __shared__ float Vt[4096];   // 64 x 64 V

    const int ch = blockIdx.x % nch;
    const int bh = blockIdx.x / nch;
    const int b = bh / H_, h = bh % H_;
    const int tid = threadIdx.x;
    const int w = tid >> 6, lane = tid & 63;
    const int rr = tid >> 4, c4 = (tid & 15) << 2;   // staging row-group, col
    const int Dw = (w & 1) << 5, Ew = (w >> 1) << 5; // quadrant base
    const int d0 = Dw + ((lane >> 3) << 2);          // 4 d's per lane
    const int e0 = Ew + ((lane & 7) << 2);           // 4 e's per lane
    const bool doks = (Ew == 0);                     // wave-uniform

    const size_t gbase = (size_t)(b * L_ + ch * rowsPerCh) * E_ + h * D_ + c4;
    const int nr = rowsPerCh >> 6;

    float4 kreg[4], vreg[4];
    float acc[4][4];
    #pragma unroll
    for (int i = 0; i < 4; ++i)
        #pragma unroll
        for (int j = 0; j < 4; ++j) acc[i][j] = 0.f;
    float ks[4] = {0.f, 0.f, 0.f, 0.f};

    // prologue: round-0 loads
    #pragma unroll
    for (int i = 0; i < 4; ++i) {
        const size_t g = gbase + (size_t)(rr + (i << 4)) * E_;
        kreg[i] = *(const float4*)(K + g);
        vreg[i] = *(const float4*)(V + g);
    }

    for (int t = 0; t < nr; ++t) {
        #pragma unroll
        for (int i = 0; i < 4; ++i) {
            const int row = rr + (i << 4);
            float4 pk;
            pk.x = sigk(kreg[i].x); pk.y = sigk(kreg[i].y);
            pk.z = sigk(kreg[i].z); pk.w = sigk(kreg[i].w);
            *(float4*)(Kt + (row << 6) + c4) = pk;
            *(float4*)(Vt + (row << 6) + c4) = vreg[i];
        }
        __syncthreads();
        if (t + 1 < nr) {   // issue next round's loads; land during compute
            #pragma unroll
            for (int i = 0; i < 4; ++i) {
                const size_t g = gbase +
                    (size_t)(((t + 1) << 6) + rr + (i << 4)) * E_;
                kreg[i] = *(const float4*)(K + g);
                vreg[i] = *(const float4*)(V + g);
            }
        }
        // sweep all 64 rows; K/V reads cover each bank exactly once
        // (8 distinct f4 per wave, 8-lane broadcast) -> conflict-free
        const float* kp = Kt + d0;
        const float* vp = Vt + e0;
        if (doks) {
            #pragma unroll 4
            for (int kk = 0; kk < 64; ++kk) {
                const float4 ka = *(const float4*)kp;
                const float4 vb = *(const float4*)vp;
                const float av[4] = {ka.x, ka.y, ka.z, ka.w};
                const float bv[4] = {vb.x, vb.y, vb.z, vb.w};
                #pragma unroll
                for (int i = 0; i < 4; ++i) {
                    #pragma unroll
                    for (int j = 0; j < 4; ++j)
                        acc[i][j] = fmaf(av[i], bv[j], acc[i][j]);
                    ks[i] += av[i];
                }
                kp += 64; vp += 64;
            }
        } else {
            #pragma unroll 4
            for (int kk = 0; kk < 64; ++kk) {
                const float4 ka = *(const float4*)kp;
                const float4 vb = *(const float4*)vp;
                const float av[4] = {ka.x, ka.y, ka.z, ka.w};
                const float bv[4] = {vb.x, vb.y, vb.z, vb.w};
                #pragma unroll
                for (int i = 0; i < 4; ++i)
                    #pragma unroll
                    for (int j = 0; j < 4; ++j)
                        acc[i][j] = fmaf(av[i], bv[j], acc[i][j]);
                kp += 64; vp += 64;
            }
        }
        __syncthreads();
    }

    // store quadrant directly (no inter-wave reduce)
    const size_t pbase = ((size_t)ch * BH_ + bh) * (size_t)STATE_;
    #pragma unroll
    for (int i = 0; i < 4; ++i) {
        *(float4*)(partial + pbase + (size_t)(d0 + i) * 64 + e0) =
            make_float4(acc[i][0], acc[i][1], acc[i][2], acc[i][3]);
    }
    if (doks && (lane & 7) == 0) {
        #pragma unroll
        for (int i = 0; i < 4; ++i)
            partial[pbase + 4096 + d0 + i] = ks[i];
    }
}

// ---------------- Kernel 2: reduce partials -> final KV state ----------------
__global__ void __launch_bounds__(256) kv_reduce_kernel(
    const float* __restrict__ partial, float* __restrict__ kv, int nch)
{
    const int total = BH_ * STATE_;
    const int idx = blockIdx.x * 256 + threadIdx.x;
    if (idx >= total) return;
    float s = 0.f;
    for (int c = 0; c < nch; ++c) s += partial[(size_t)c * total + idx];
    kv[idx] = s;
}

// ---------------- Kernel 3: out = (phiQ @ kv) / (phiQ @ ksum) ----------------
// 128-row q-tiles, 2 threads/row x 32 contiguous e each: halves redundant
// sigmoid (vs 4 threads/row) and halves kvs staging traffic; each lane-pair
// stores a contiguous 256B row segment.
__global__ void __launch_bounds__(256) attn_out_kernel(
    const float* __restrict__ Q, const float* __restrict__ kv,
    float* __restrict__ out)
{
    __shared__ float kvs[STATE_];
    const int bh = blockIdx.x >> 5;          // 32 q-tiles of 128 rows per (b,h)
    const int qt = blockIdx.x & 31;
    const int b = bh / H_, h = bh % H_;
    const int tid = threadIdx.x;
    {
        const float4* src = (const float4*)(kv + (size_t)bh * STATE_);
        float4* dst = (float4*)kvs;
        for (int i = tid; i < STATE_ / 4; i += 256) dst[i] = src[i];
    }
    __syncthreads();

    const int rq = tid >> 1;             // 0..127: q-row within tile
    const int eh = (tid & 1) << 5;       // e-half: 0 or 32
    const int row = qt * 128 + rq;
    const float4* qp = (const float4*)(Q + ((size_t)b * L_ + row) * E_ + h * D_);

    float4 acc[8];
    #pragma unroll
    for (int j = 0; j < 8; ++j) acc[j] = make_float4(0.f, 0.f, 0.f, 0.f);
    float den = 0.f;

    #pragma unroll 4
    for (int jj = 0; jj < 16; ++jj) {
        const float4 a = qp[jj];
        const float p[4] = {sigk(a.x), sigk(a.y), sigk(a.z), sigk(a.w)};
        const int dbase = jj << 2;
        #pragma unroll
        for (int i = 0; i < 4; ++i) {
            const float s = p[i];
            den = fmaf(s, kvs[4096 + dbase + i], den);   // uniform broadcast
            const float* krow = kvs + (size_t)(dbase + i) * 64 + eh;
            #pragma unroll
            for (int j = 0; j < 8; ++j) {
                const float4 v = *(const float4*)(krow + (j << 2));
                acc[j].x = fmaf(s, v.x, acc[j].x);
                acc[j].y = fmaf(s, v.y, acc[j].y);
                acc[j].z = fmaf(s, v.z, acc[j].z);
                acc[j].w = fmaf(s, v.w, acc[j].w);
            }
        }
    }

    const float inv = __builtin_amdgcn_rcpf(den);
    float* op = out + ((size_t)b * L_ + row) * E_ + h * D_ + eh;
    #pragma unroll
    for (int j = 0; j < 8; ++j) {
        float4 o;
        o.x = acc[j].x * inv; o.y = acc[j].y * inv;
        o.z = acc[j].z * inv; o.w = acc[j].w * inv;
        *(float4*)(op + (j << 2)) = o;
    }
}

extern "C" void kernel_launch(void* const* d_in, const int* in_sizes, int n_in,
                              void* d_out, int out_size, void* d_ws, size_t ws_size,
                              hipStream_t stream) {
    const float* Q = (const float*)d_in[0];
    const float* K = (const float*)d_in[1];
    const float* V = (const float*)d_in[2];
    float* out = (float*)d_out;

    float* kv      = (float*)d_ws;                 // BH_*STATE_ floats (~1 MiB)
    float* partial = kv + (size_t)BH_ * STATE_;    // nch*BH_*STATE_ floats

    int nch = 16;
    while (nch > 1 &&
           (size_t)(1 + nch) * BH_ * STATE_ * sizeof(float) > ws_size)
        nch >>= 1;
    const int rowsPerCh = L_ / nch;

    hipLaunchKernelGGL(kv_partial_kernel, dim3(BH_ * nch), dim3(256), 0, stream,
                       K, V, partial, nch, rowsPerCh);

    const int total = BH_ * STATE_;
    hipLaunchKernelGGL(kv_reduce_kernel, dim3((total + 255) / 256), dim3(256), 0, stream,
                       partial, kv, nch);

    hipLaunchKernelGGL(attn_out_kernel, dim3(BH_ * (L_ / 128)), dim3(256), 0, stream,
                       Q, kv, out);
}